// Round 1
// baseline (153.844 us; speedup 1.0000x reference)
//
#include <hip/hip_runtime.h>

// Problem constants: N=1024, C=32, T=8, V=64, K=3, CT=256
// out[n][c][v][t] = sum_k sum_j W[k][c*8+t][j] * U_k[j][v] + bias2T[c*8+t][v]
// U_k[j][v] = sum_u x[n][j][u] * A[k][u][v]   (j = ct index 0..255, u,v = nodes)

typedef __attribute__((ext_vector_type(8))) short bf16x8;
typedef __attribute__((ext_vector_type(4))) float f32x4;

__device__ __forceinline__ short f2bf(float f) {
  union { float f; unsigned u; } c; c.f = f;
  unsigned r = c.u + 0x7FFFu + ((c.u >> 16) & 1u);   // round-to-nearest-even
  return (short)(r >> 16);
}

// ---------------- workspace layout (bytes) ----------------
// Wsw   : short[196608] @ 0        fragment-ordered W  (k,wv,mt,ks,lane,e)
// Asw   : short[12288]  @ 393216   fragment-ordered A^T (k,ks,nt,lane,e)
// bias2T: float[16384]  @ 417792   bias2T[d][w]
#define ASW_OFF  393216
#define BIAS_OFF 417792

__global__ __launch_bounds__(256) void prep_kernel(
    const float* __restrict__ W, const float* __restrict__ b,
    const float* __restrict__ A, short* __restrict__ Wsw,
    short* __restrict__ Asw, float* __restrict__ bias2T) {
  int t = blockIdx.x * 256 + threadIdx.x;
  if (t < 196608) {
    // Wsw flat = ((((k*4+wv)*4+mt)*8+ks)*64 + lane)*8 + e
    int e = t & 7, l = (t >> 3) & 63, ks = (t >> 9) & 7, mt = (t >> 12) & 3,
        wv = (t >> 14) & 3, k = t >> 16;
    int d = wv * 64 + mt * 16 + (l & 15);
    int c = ks * 32 + (l >> 4) * 8 + e;
    Wsw[t] = f2bf(W[(k * 256 + d) * 256 + c]);
  } else if (t < 196608 + 12288) {
    // Asw flat = (((k*2+ks)*4+nt)*64 + lane)*8 + e ; value = A[k][v][w]
    int t2 = t - 196608;
    int e = t2 & 7, l = (t2 >> 3) & 63, nt = (t2 >> 9) & 3, ks = (t2 >> 11) & 1,
        k = t2 >> 12;
    int w = nt * 16 + (l & 15);
    int v = ks * 32 + (l >> 4) * 8 + e;
    Asw[t2] = f2bf(A[(k * 64 + v) * 64 + w]);
  } else {
    int t2 = t - 196608 - 12288;
    int d = t2 >> 6, w = t2 & 63;
    float s = 0.f;
    for (int k = 0; k < 3; ++k) {
      float cs = 0.f;
      for (int v = 0; v < 64; ++v) cs += A[(k * 64 + v) * 64 + w];
      s += cs * b[k * 256 + d];
    }
    bias2T[t2] = s;
  }
}

#define UT_STRIDE 264  // bf16 elems per Ut row (256 + 8 pad; 528B, 16B-aligned, bank-adv 4)

__global__ __launch_bounds__(256, 2) void gcn_main(
    const float* __restrict__ x, const short* __restrict__ Wsw,
    const short* __restrict__ Asw, const float* __restrict__ bias2T,
    float* __restrict__ out) {
  __shared__ short Ut[64 * UT_STRIDE];  // Ut[w][ct] = U[ct][w], 33792 B

  const int tid = threadIdx.x;
  const int wv = tid >> 6;        // wave id 0..3
  const int lane = tid & 63;
  const int li = lane & 15;       // intra-tile col/row index
  const int lq = lane >> 4;       // quad 0..3
  const int n = blockIdx.x;

  const float* xn = x + (size_t)n * 16384;

  // ---- stage-1 A-operand: this wave's 64x64 block of Xn, in registers (k-invariant)
  // af frag (ks,mt): A[m = 64wv+mt*16+li][kdim = ks*32 + lq*8 + j]
  bf16x8 xf[2][4];
#pragma unroll
  for (int ks = 0; ks < 2; ++ks)
#pragma unroll
    for (int mt = 0; mt < 4; ++mt) {
      int row = 64 * wv + mt * 16 + li;
      int v0 = ks * 32 + lq * 8;
      const float4* p = (const float4*)(xn + row * 64 + v0);
      float4 f0 = p[0], f1 = p[1];
      bf16x8 tt;
      tt[0] = f2bf(f0.x); tt[1] = f2bf(f0.y); tt[2] = f2bf(f0.z); tt[3] = f2bf(f0.w);
      tt[4] = f2bf(f1.x); tt[5] = f2bf(f1.y); tt[6] = f2bf(f1.z); tt[7] = f2bf(f1.w);
      xf[ks][mt] = tt;
    }

  f32x4 acc2[4][4];
#pragma unroll
  for (int mt = 0; mt < 4; ++mt)
#pragma unroll
    for (int nt = 0; nt < 4; ++nt)
      acc2[mt][nt] = (f32x4){0.f, 0.f, 0.f, 0.f};

  for (int k = 0; k < 3; ++k) {
    // ---------- stage 1: U_k rows [64wv, 64wv+64), all 64 cols ----------
    f32x4 acc1[4][4];
#pragma unroll
    for (int mt = 0; mt < 4; ++mt)
#pragma unroll
      for (int nt = 0; nt < 4; ++nt)
        acc1[mt][nt] = (f32x4){0.f, 0.f, 0.f, 0.f};

    const short* AswK = Asw + k * 4096;
#pragma unroll
    for (int ks = 0; ks < 2; ++ks) {
      bf16x8 bfr[4];
#pragma unroll
      for (int nt = 0; nt < 4; ++nt)
        bfr[nt] = *(const bf16x8*)(AswK + ((ks * 4 + nt) * 64 + lane) * 8);
#pragma unroll
      for (int mt = 0; mt < 4; ++mt)
#pragma unroll
        for (int nt = 0; nt < 4; ++nt)
          acc1[mt][nt] = __builtin_amdgcn_mfma_f32_16x16x32_bf16(
              xf[ks][mt], bfr[nt], acc1[mt][nt], 0, 0, 0);
    }

    __syncthreads();  // previous stage-2 readers done with Ut

    // write U_k -> Ut (transposed), 4 consecutive ct per lane packed into b64
#pragma unroll
    for (int mt = 0; mt < 4; ++mt)
#pragma unroll
      for (int nt = 0; nt < 4; ++nt) {
        int w = nt * 16 + li;
        int ct = 64 * wv + mt * 16 + 4 * lq;
        union { short s[4]; unsigned long long u; } p;
        p.s[0] = f2bf(acc1[mt][nt][0]);
        p.s[1] = f2bf(acc1[mt][nt][1]);
        p.s[2] = f2bf(acc1[mt][nt][2]);
        p.s[3] = f2bf(acc1[mt][nt][3]);
        *(unsigned long long*)(&Ut[w * UT_STRIDE + ct]) = p.u;
      }

    __syncthreads();  // Ut ready for all waves

    // ---------- stage 2: acc2 += W_k[rows 64wv..] @ U_k ----------
    const short* WswK = Wsw + (k * 4 + wv) * 16384;
#pragma unroll
    for (int ks = 0; ks < 8; ++ks) {
      bf16x8 aw[4], bu[4];
#pragma unroll
      for (int mt = 0; mt < 4; ++mt)
        aw[mt] = *(const bf16x8*)(WswK + ((mt * 8 + ks) * 64 + lane) * 8);
#pragma unroll
      for (int nt = 0; nt < 4; ++nt)
        bu[nt] = *(const bf16x8*)(&Ut[(nt * 16 + li) * UT_STRIDE + ks * 32 + lq * 8]);
#pragma unroll
      for (int mt = 0; mt < 4; ++mt)
#pragma unroll
        for (int nt = 0; nt < 4; ++nt)
          acc2[mt][nt] = __builtin_amdgcn_mfma_f32_16x16x32_bf16(
              aw[mt], bu[nt], acc2[mt][nt], 0, 0, 0);
    }
  }

  __syncthreads();  // all Ut reads done -> LDS reusable for epilogue

  // ---------- epilogue: +bias, (d,w) -> out[n][c][v][t], via per-wave LDS bounce ----------
  // wave region: 2112 floats of the (dead) Ut buffer; two passes of 32 d-rows
  float* ep = ((float*)Ut) + wv * 2112;  // need 32*65 = 2080 per pass
  float* outn = out + (size_t)n * 16384 + wv * 4096;

#pragma unroll
  for (int pass = 0; pass < 2; ++pass) {
#pragma unroll
    for (int mth = 0; mth < 2; ++mth) {
      int mt = pass * 2 + mth;
#pragma unroll
      for (int nt = 0; nt < 4; ++nt) {
        int w = nt * 16 + li;
#pragma unroll
        for (int r = 0; r < 4; ++r) {
          int dl = mt * 16 + 4 * lq + r;          // d within wave's 64 rows
          int dl2 = dl - pass * 32;               // d within pass (0..31)
          ep[dl2 * 65 + w] =
              acc2[mt][nt][r] + bias2T[(64 * wv + dl) * 64 + w];
        }
      }
    }
    // read out in output order, coalesced float4 stores (same-wave LDS ordering)
#pragma unroll
    for (int it = 0; it < 8; ++it) {
      int jj2 = it * 256 + lane * 4;              // 0..2047 within pass
      int cl2 = jj2 >> 9;                         // 0..3
      int w = (jj2 >> 3) & 63;
      int t0 = jj2 & 7;                           // 0 or 4
      float4 vv;
      vv.x = ep[(cl2 * 8 + t0 + 0) * 65 + w];
      vv.y = ep[(cl2 * 8 + t0 + 1) * 65 + w];
      vv.z = ep[(cl2 * 8 + t0 + 2) * 65 + w];
      vv.w = ep[(cl2 * 8 + t0 + 3) * 65 + w];
      *(float4*)(outn + pass * 2048 + jj2) = vv;
    }
  }
}

extern "C" void kernel_launch(void* const* d_in, const int* in_sizes, int n_in,
                              void* d_out, int out_size, void* d_ws, size_t ws_size,
                              hipStream_t stream) {
  (void)in_sizes; (void)n_in; (void)out_size; (void)ws_size;
  const float* x = (const float*)d_in[0];
  const float* W = (const float*)d_in[1];
  const float* b = (const float*)d_in[2];
  const float* A = (const float*)d_in[3];
  float* out = (float*)d_out;

  short* Wsw = (short*)d_ws;
  short* Asw = (short*)((char*)d_ws + ASW_OFF);
  float* bias2T = (float*)((char*)d_ws + BIAS_OFF);

  // prep: 196608 (W) + 12288 (A) + 16384 (bias) = 225280 threads = 880 blocks
  prep_kernel<<<880, 256, 0, stream>>>(W, b, A, Wsw, Asw, bias2T);
  gcn_main<<<1024, 256, 0, stream>>>(x, Wsw, Asw, bias2T, out);
}